// Round 1
// baseline (1367.031 us; speedup 1.0000x reference)
//
#include <hip/hip_runtime.h>
#include <cmath>

typedef _Float16 f16;
typedef _Float16 f16x4 __attribute__((ext_vector_type(4)));
typedef _Float16 f16x8 __attribute__((ext_vector_type(8)));
typedef float f32x4 __attribute__((ext_vector_type(4)));

// Dims: V=32000 E=256 H=256 B=64 S=32 T=32; decoder hidden 2H=512.
// MENC = S*B = 2048 rows; MDEC = (T-1)*B = 1984 rows.

// ---------------- workspace layout (bytes) ----------------
static constexpr size_t OFF_WIHF = 0;                                 // 768x256 f16
static constexpr size_t OFF_WHHF = OFF_WIHF + 768UL*256*2;
static constexpr size_t OFF_WIHB = OFF_WHHF + 768UL*256*2;
static constexpr size_t OFF_WHHB = OFF_WIHB + 768UL*256*2;
static constexpr size_t OFF_WIHD = OFF_WHHB + 768UL*256*2;            // 1536x768 f16
static constexpr size_t OFF_WHHD = OFF_WIHD + 1536UL*768*2;           // 1536x512 f16
static constexpr size_t OFF_FCW  = OFF_WHHD + 1536UL*512*2;           // 32000x512 f16
static constexpr size_t OFF_XENC = OFF_FCW  + 32000UL*512*2;          // 2048x256 f16
static constexpr size_t OFF_XDEC = OFF_XENC + 2048UL*256*2;           // 1984x256 f16
static constexpr size_t OFF_GIF  = OFF_XDEC + 1984UL*256*2;           // 2048x768 f32
static constexpr size_t OFF_GIB  = OFF_GIF  + 2048UL*768*4;
static constexpr size_t OFF_GITOK= OFF_GIB  + 2048UL*768*4;           // 1984x1536 f32
static constexpr size_t OFF_GICTX= OFF_GITOK+ 1984UL*1536*4;          // 64x1536 f32
static constexpr size_t OFF_CTX32= OFF_GICTX+ 64UL*1536*4;            // 64x512 f32
static constexpr size_t OFF_CTX16= OFF_CTX32+ 64UL*512*4;             // 64x512 f16
static constexpr size_t OFF_HPP  = OFF_CTX16+ 64UL*512*2;             // 2dir x 2buf x 64x256 f16
static constexpr size_t OFF_HALL = OFF_HPP  + 2UL*2*64*256*2;         // 2048x512 f16 (rows>=1984 unused)
static constexpr size_t OFF_BAR  = OFF_HALL + 2048UL*512*2;           // 8 ints

__device__ __forceinline__ float sigmoidf_(float x) { return 1.f / (1.f + __expf(-x)); }

// Agent-scope grid barrier (generation counter). 16 co-resident WGs only.
__device__ __forceinline__ void gbar(int* cnt, int* gen, int nwg) {
  __syncthreads();
  if (threadIdx.x == 0) {
    __threadfence();
    int g = __hip_atomic_load(gen, __ATOMIC_RELAXED, __HIP_MEMORY_SCOPE_AGENT);
    int a = __hip_atomic_fetch_add(cnt, 1, __ATOMIC_ACQ_REL, __HIP_MEMORY_SCOPE_AGENT);
    if (a == nwg - 1) {
      __hip_atomic_store(cnt, 0, __ATOMIC_RELAXED, __HIP_MEMORY_SCOPE_AGENT);
      __hip_atomic_fetch_add(gen, 1, __ATOMIC_ACQ_REL, __HIP_MEMORY_SCOPE_AGENT);
    } else {
      while (__hip_atomic_load(gen, __ATOMIC_ACQUIRE, __HIP_MEMORY_SCOPE_AGENT) == g) {
        __builtin_amdgcn_s_sleep(2);
      }
    }
    __threadfence();
  }
  __syncthreads();
}

// ---------------- K1: fp32 -> fp16 weight conversion (one pass) ----------------
__global__ void k_convert(const float* __restrict__ wihf, const float* __restrict__ whhf,
                          const float* __restrict__ wihb, const float* __restrict__ whhb,
                          const float* __restrict__ wihd, const float* __restrict__ whhd,
                          const float* __restrict__ fcw,
                          f16* dWihf, f16* dWhhf, f16* dWihb, f16* dWhhb,
                          f16* dWihd, f16* dWhhd, f16* dFcw) {
  const long stride = (long)gridDim.x * blockDim.x;
  for (long i = (long)blockIdx.x * blockDim.x + threadIdx.x; i < 4784128L; i += stride) {
    const float* s; f16* d; long j = i;
    if (j < 49152L)        { s = wihf; d = dWihf; }
    else if (j < 98304L)   { s = whhf; d = dWhhf; j -= 49152L; }
    else if (j < 147456L)  { s = wihb; d = dWihb; j -= 98304L; }
    else if (j < 196608L)  { s = whhb; d = dWhhb; j -= 147456L; }
    else if (j < 491520L)  { s = wihd; d = dWihd; j -= 196608L; }
    else if (j < 688128L)  { s = whhd; d = dWhhd; j -= 491520L; }
    else                   { s = fcw;  d = dFcw;  j -= 688128L; }
    float4 v = ((const float4*)s)[j];
    f16x4 o; o.x = (f16)v.x; o.y = (f16)v.y; o.z = (f16)v.z; o.w = (f16)v.w;
    ((f16x4*)d)[j] = o;
  }
}

// ---------------- K2: embedding gather (f16) + zero out[:,0,:] + barrier init ----------------
__global__ void k_gather(const int* __restrict__ srct, const int* __restrict__ trgt,
                         const float* __restrict__ embe, const float* __restrict__ embd,
                         f16* __restrict__ Xenc, f16* __restrict__ Xdec,
                         float* __restrict__ out, int* __restrict__ bar) {
  long tid = (long)blockIdx.x * blockDim.x + threadIdx.x;
  long stride = (long)gridDim.x * blockDim.x;
  if (tid < 8) bar[tid] = 0;
  // gather: rows 0..2047 -> Xenc (m = s*64+b), rows 2048..4031 -> Xdec (m = t*64+b)
  for (long i = tid; i < 4032L * 64; i += stride) {
    int row = (int)(i >> 6), j4 = (int)(i & 63);
    const float* e; f16* d; int tok;
    if (row < 2048) {
      int s = row >> 6, b = row & 63;
      tok = srct[b * 32 + s]; e = embe; d = Xenc + (long)row * 256;
    } else {
      int rd = row - 2048; int t = rd >> 6, b = rd & 63;
      tok = trgt[b * 32 + t]; e = embd; d = Xdec + (long)rd * 256;
    }
    float4 v = ((const float4*)(e + (long)tok * 256))[j4];
    f16x4 o; o.x = (f16)v.x; o.y = (f16)v.y; o.z = (f16)v.z; o.w = (f16)v.w;
    ((f16x4*)d)[j4] = o;
  }
  // zero out[:, 0, :]
  for (long i = tid; i < 64L * 8000; i += stride) {
    long b = i / 8000, j = i % 8000;
    float4 z = make_float4(0.f, 0.f, 0.f, 0.f);
    ((float4*)(out + b * 1024000L))[j] = z;
  }
}

// ---------------- K3: generic small GEMM  C[M,N] = A[M,K]f16 @ B[N,K]f16^T (+bias) ----------------
// grid (M/64, N/64), block 256. Wave w does rows [w*16, w*16+16).
__global__ __launch_bounds__(256) void k_gemm(const f16* __restrict__ A, int lda,
                                              const f16* __restrict__ B, int ldb,
                                              const float* __restrict__ bias,
                                              float* __restrict__ C, int ldc, int Ksteps) {
  int m0 = blockIdx.x * 64, n0 = blockIdx.y * 64;
  int lane = threadIdx.x & 63, w = threadIdx.x >> 6;
  int ar = m0 + w * 16 + (lane & 15);
  int koff = (lane >> 4) * 8;
  f32x4 acc[4] = {};
  for (int ks = 0; ks < Ksteps; ks++) {
    f16x8 a = *(const f16x8*)(A + (size_t)ar * lda + ks * 32 + koff);
#pragma unroll
    for (int ni = 0; ni < 4; ni++) {
      const f16* bp = B + (size_t)(n0 + ni * 16 + (lane & 15)) * ldb + ks * 32 + koff;
      f16x8 b = *(const f16x8*)bp;
      acc[ni] = __builtin_amdgcn_mfma_f32_16x16x32_f16(a, b, acc[ni], 0, 0, 0);
    }
  }
  int dm = m0 + w * 16 + ((lane >> 4) << 2);
  int dn0 = n0 + (lane & 15);
#pragma unroll
  for (int ni = 0; ni < 4; ni++) {
    int n = dn0 + ni * 16;
    float bv = bias ? bias[n] : 0.f;
#pragma unroll
    for (int r = 0; r < 4; r++) C[(size_t)(dm + r) * ldc + n] = acc[ni][r] + bv;
  }
}

// ---------------- K4: encoder bidirectional GRU recurrence (persistent, 16 WGs) ----------------
__global__ void k_enc(const float* __restrict__ giF, const float* __restrict__ giB,
                      const f16* __restrict__ WhhF, const f16* __restrict__ WhhB,
                      const float* __restrict__ bhhF, const float* __restrict__ bhhB,
                      f16* __restrict__ hpp, float* __restrict__ ctx32, f16* __restrict__ ctx16,
                      int* __restrict__ bar) {
  int w = blockIdx.x;
  int dir = w >> 3, mb = (w >> 2) & 1, cg = w & 3;
  int tid = threadIdx.x, lane = tid & 63, wv = tid >> 6;
  int mh = wv >> 1, ch = wv & 1;
  const float* gi = dir ? giB : giF;
  const f16* Whh = dir ? WhhB : WhhF;
  const float* bhh = dir ? bhhB : bhhF;
  f16* hb = hpp + (size_t)dir * (2 * 64 * 256);
  { // zero ping-pong buffer 0 of this dir (8 blocks x 256 thr x 8 halves = 16384)
    int idx0 = ((w & 7) * 256 + tid) * 8;
    f16x8 z = {};
    *(f16x8*)(hb + idx0) = z;
  }
  int colb = cg * 64 + ch * 32 + (lane & 15);
  float bh[3][2];
#pragma unroll
  for (int q = 0; q < 3; q++) {
#pragma unroll
    for (int i = 0; i < 2; i++) bh[q][i] = bhh[q * 256 + colb + i * 16];
  }
  float ho[2][4] = {};
  int rowA = mb * 32 + mh * 16 + (lane & 15);
  int rowD = mb * 32 + mh * 16 + ((lane >> 4) << 2);
  int koff = (lane >> 4) * 8;
  gbar(bar + 0, bar + 1, 16);
  for (int s = 0; s < 32; s++) {
    const f16* hr = hb + (s & 1) * (64 * 256);
    f16* hw = hb + ((s + 1) & 1) * (64 * 256);
    int sgi = dir ? (31 - s) : s;
    const float* gis = gi + (size_t)sgi * (64 * 768);
    f32x4 acc[3][2] = {};
#pragma unroll
    for (int ks = 0; ks < 8; ks++) {
      f16x8 a = *(const f16x8*)(hr + rowA * 256 + ks * 32 + koff);
#pragma unroll
      for (int q = 0; q < 3; q++) {
#pragma unroll
        for (int i = 0; i < 2; i++) {
          int n = q * 256 + colb + i * 16;
          f16x8 b = *(const f16x8*)(Whh + (size_t)n * 256 + ks * 32 + koff);
          acc[q][i] = __builtin_amdgcn_mfma_f32_16x16x32_f16(a, b, acc[q][i], 0, 0, 0);
        }
      }
    }
#pragma unroll
    for (int i = 0; i < 2; i++) {
      int col = colb + i * 16;
#pragma unroll
      for (int r = 0; r < 4; r++) {
        int m = rowD + r;
        const float* g = gis + (size_t)m * 768;
        float rg = sigmoidf_(g[col] + acc[0][i][r] + bh[0][i]);
        float zg = sigmoidf_(g[256 + col] + acc[1][i][r] + bh[1][i]);
        float ng = tanhf(g[512 + col] + rg * (acc[2][i][r] + bh[2][i]));
        float h = (1.f - zg) * ng + zg * ho[i][r];
        ho[i][r] = h;
        hw[m * 256 + col] = (f16)h;
      }
    }
    gbar(bar + 0, bar + 1, 16);
  }
  // context = [h_fwd, h_bwd]
#pragma unroll
  for (int i = 0; i < 2; i++) {
#pragma unroll
    for (int r = 0; r < 4; r++) {
      int m = rowD + r, c = dir * 256 + colb + i * 16;
      ctx32[m * 512 + c] = ho[i][r];
      ctx16[m * 512 + c] = (f16)ho[i][r];
    }
  }
}

// ---------------- K6: decoder GRU recurrence (persistent, 16 WGs) ----------------
__global__ void k_dec(const float* __restrict__ giTok, const float* __restrict__ giCtx,
                      const f16* __restrict__ Whh, const float* __restrict__ bhh,
                      const float* __restrict__ ctx32, const f16* __restrict__ ctx16,
                      f16* __restrict__ Hall, int* __restrict__ bar) {
  int w = blockIdx.x;
  int mb = w >> 3, cg = w & 7;
  int tid = threadIdx.x, lane = tid & 63, wv = tid >> 6;
  int mh = wv >> 1, ch = wv & 1;
  int colb = cg * 64 + ch * 32 + (lane & 15);
  int rowA = mb * 32 + mh * 16 + (lane & 15);
  int rowD = mb * 32 + mh * 16 + ((lane >> 4) << 2);
  int koff = (lane >> 4) * 8;
  float bh[3][2], gc[3][2][4], ho[2][4];
#pragma unroll
  for (int q = 0; q < 3; q++) {
#pragma unroll
    for (int i = 0; i < 2; i++) {
      bh[q][i] = bhh[q * 512 + colb + i * 16];
#pragma unroll
      for (int r = 0; r < 4; r++)
        gc[q][i][r] = giCtx[(size_t)(rowD + r) * 1536 + q * 512 + colb + i * 16];
    }
  }
#pragma unroll
  for (int i = 0; i < 2; i++) {
#pragma unroll
    for (int r = 0; r < 4; r++) ho[i][r] = ctx32[(rowD + r) * 512 + colb + i * 16];
  }
  for (int t = 0; t < 31; t++) {
    const f16* hr = t ? (Hall + (size_t)(t - 1) * (64 * 512)) : ctx16;
    f16* hw = Hall + (size_t)t * (64 * 512);
    const float* gt = giTok + (size_t)t * (64 * 1536);
    f32x4 acc[3][2] = {};
#pragma unroll
    for (int ks = 0; ks < 16; ks++) {
      f16x8 a = *(const f16x8*)(hr + rowA * 512 + ks * 32 + koff);
#pragma unroll
      for (int q = 0; q < 3; q++) {
#pragma unroll
        for (int i = 0; i < 2; i++) {
          int n = q * 512 + colb + i * 16;
          f16x8 b = *(const f16x8*)(Whh + (size_t)n * 512 + ks * 32 + koff);
          acc[q][i] = __builtin_amdgcn_mfma_f32_16x16x32_f16(a, b, acc[q][i], 0, 0, 0);
        }
      }
    }
#pragma unroll
    for (int i = 0; i < 2; i++) {
      int col = colb + i * 16;
#pragma unroll
      for (int r = 0; r < 4; r++) {
        int m = rowD + r;
        const float* g = gt + (size_t)m * 1536;
        float rg = sigmoidf_(g[col] + gc[0][i][r] + acc[0][i][r] + bh[0][i]);
        float zg = sigmoidf_(g[512 + col] + gc[1][i][r] + acc[1][i][r] + bh[1][i]);
        float ng = tanhf(g[1024 + col] + gc[2][i][r] + rg * (acc[2][i][r] + bh[2][i]));
        float h = (1.f - zg) * ng + zg * ho[i][r];
        ho[i][r] = h;
        hw[m * 512 + col] = (f16)h;
      }
    }
    gbar(bar + 2, bar + 3, 16);
  }
}

// ---------------- K7: FC GEMM  out[b, t+1, :] = Hall[t*64+b, :] @ fcW^T + fcb ----------------
// 128x128 tile, BK=64, 256 thr, reg-staged LDS.
__global__ __launch_bounds__(256) void k_fc(const f16* __restrict__ Hall, const f16* __restrict__ Wfc,
                                            const float* __restrict__ fcb, float* __restrict__ out) {
  __shared__ f16 As[128 * 64];
  __shared__ f16 Bs[128 * 64];
  int bid = blockIdx.x;
  int by = bid / 250, bx = bid % 250;
  int m0 = by * 128, n0 = bx * 128;
  int tid = threadIdx.x, lane = tid & 63, wv = tid >> 6;
  int wm = wv >> 1, wn = wv & 1;
  f32x4 acc[4][4] = {};
  for (int kk = 0; kk < 8; kk++) {
    f16x8 ra[4], rb[4];
#pragma unroll
    for (int c = 0; c < 4; c++) {
      int seg = c * 256 + tid;
      int row = seg >> 3, ko = (seg & 7) * 8;
      ra[c] = *(const f16x8*)(Hall + (size_t)(m0 + row) * 512 + kk * 64 + ko);
      rb[c] = *(const f16x8*)(Wfc + (size_t)(n0 + row) * 512 + kk * 64 + ko);
    }
    __syncthreads();
#pragma unroll
    for (int c = 0; c < 4; c++) {
      int seg = c * 256 + tid;
      *(f16x8*)&As[seg * 8] = ra[c];
      *(f16x8*)&Bs[seg * 8] = rb[c];
    }
    __syncthreads();
#pragma unroll
    for (int ks = 0; ks < 2; ks++) {
      f16x8 af[4], bf[4];
#pragma unroll
      for (int mi = 0; mi < 4; mi++)
        af[mi] = *(const f16x8*)&As[(wm * 64 + mi * 16 + (lane & 15)) * 64 + ks * 32 + (lane >> 4) * 8];
#pragma unroll
      for (int ni = 0; ni < 4; ni++)
        bf[ni] = *(const f16x8*)&Bs[(wn * 64 + ni * 16 + (lane & 15)) * 64 + ks * 32 + (lane >> 4) * 8];
#pragma unroll
      for (int mi = 0; mi < 4; mi++) {
#pragma unroll
        for (int ni = 0; ni < 4; ni++)
          acc[mi][ni] = __builtin_amdgcn_mfma_f32_16x16x32_f16(af[mi], bf[ni], acc[mi][ni], 0, 0, 0);
      }
    }
  }
  int dn0 = n0 + wn * 64 + (lane & 15);
  float bv[4];
#pragma unroll
  for (int ni = 0; ni < 4; ni++) bv[ni] = fcb[dn0 + ni * 16];
#pragma unroll
  for (int mi = 0; mi < 4; mi++) {
    int mbase = m0 + wm * 64 + mi * 16 + ((lane >> 4) << 2);
#pragma unroll
    for (int r = 0; r < 4; r++) {
      int m = mbase + r;
      if (m < 1984) {
        int t = m >> 6, b = m & 63;
        float* orow = out + (size_t)b * 1024000 + (size_t)(t + 1) * 32000;
#pragma unroll
        for (int ni = 0; ni < 4; ni++) orow[dn0 + ni * 16] = acc[mi][ni][r] + bv[ni];
      }
    }
  }
}

extern "C" void kernel_launch(void* const* d_in, const int* in_sizes, int n_in,
                              void* d_out, int out_size, void* d_ws, size_t ws_size,
                              hipStream_t stream) {
  const int*   srct = (const int*)d_in[0];
  const int*   trgt = (const int*)d_in[1];
  const float* embe = (const float*)d_in[2];
  const float* wihf = (const float*)d_in[3];
  const float* whhf = (const float*)d_in[4];
  const float* bihf = (const float*)d_in[5];
  const float* bhhf = (const float*)d_in[6];
  const float* wihb = (const float*)d_in[7];
  const float* whhb = (const float*)d_in[8];
  const float* bihb = (const float*)d_in[9];
  const float* bhhb = (const float*)d_in[10];
  const float* embd = (const float*)d_in[11];
  const float* wihd = (const float*)d_in[12];
  const float* whhd = (const float*)d_in[13];
  const float* bihd = (const float*)d_in[14];
  const float* bhhd = (const float*)d_in[15];
  const float* fcw  = (const float*)d_in[16];
  const float* fcb  = (const float*)d_in[17];
  float* out = (float*)d_out;
  char* ws = (char*)d_ws;

  f16* W_ihf = (f16*)(ws + OFF_WIHF);
  f16* W_hhf = (f16*)(ws + OFF_WHHF);
  f16* W_ihb = (f16*)(ws + OFF_WIHB);
  f16* W_hhb = (f16*)(ws + OFF_WHHB);
  f16* W_ihd = (f16*)(ws + OFF_WIHD);
  f16* W_hhd = (f16*)(ws + OFF_WHHD);
  f16* Wfc   = (f16*)(ws + OFF_FCW);
  f16* Xenc  = (f16*)(ws + OFF_XENC);
  f16* Xdec  = (f16*)(ws + OFF_XDEC);
  float* giF   = (float*)(ws + OFF_GIF);
  float* giB   = (float*)(ws + OFF_GIB);
  float* giTok = (float*)(ws + OFF_GITOK);
  float* giCtx = (float*)(ws + OFF_GICTX);
  float* ctx32 = (float*)(ws + OFF_CTX32);
  f16*   ctx16 = (f16*)(ws + OFF_CTX16);
  f16*   hpp   = (f16*)(ws + OFF_HPP);
  f16*   Hall  = (f16*)(ws + OFF_HALL);
  int*   bar   = (int*)(ws + OFF_BAR);

  // K1: weight conversion
  k_convert<<<2048, 256, 0, stream>>>(wihf, whhf, wihb, whhb, wihd, whhd, fcw,
                                      W_ihf, W_hhf, W_ihb, W_hhb, W_ihd, W_hhd, Wfc);
  // K2: gather embeddings, zero out[:,0,:], init barriers
  k_gather<<<1024, 256, 0, stream>>>(srct, trgt, embe, embd, Xenc, Xdec, out, bar);
  // K3: batched input-side GEMMs
  k_gemm<<<dim3(32, 12), 256, 0, stream>>>(Xenc, 256, W_ihf, 256, bihf, giF, 768, 8);
  k_gemm<<<dim3(32, 12), 256, 0, stream>>>(Xenc, 256, W_ihb, 256, bihb, giB, 768, 8);
  k_gemm<<<dim3(31, 24), 256, 0, stream>>>(Xdec, 256, W_ihd, 768, nullptr, giTok, 1536, 8);
  // K4: encoder recurrence (both directions)
  k_enc<<<16, 256, 0, stream>>>(giF, giB, W_hhf, W_hhb, bhhf, bhhb, hpp, ctx32, ctx16, bar);
  // K5: context part of decoder input-side GEMM (step-invariant) + b_ih_d
  k_gemm<<<dim3(1, 24), 256, 0, stream>>>(ctx16, 512, W_ihd + 256, 768, bihd, giCtx, 1536, 16);
  // K6: decoder recurrence
  k_dec<<<16, 256, 0, stream>>>(giTok, giCtx, W_hhd, bhhd, ctx32, ctx16, Hall, bar);
  // K7: vocab projection for all 31 steps
  k_fc<<<4000, 256, 0, stream>>>(Hall, Wfc, fcb, out);
}

// Round 2
// 614.137 us; speedup vs baseline: 2.2259x; 2.2259x over previous
//
#include <hip/hip_runtime.h>
#include <cmath>

typedef _Float16 f16;
typedef _Float16 f16x4 __attribute__((ext_vector_type(4)));
typedef _Float16 f16x8 __attribute__((ext_vector_type(8)));
typedef float f32x4 __attribute__((ext_vector_type(4)));

// Dims: V=32000 E=256 H=256 B=64 S=32 T=32; decoder hidden 2H=512.

// ---------------- workspace layout (bytes) ----------------
static constexpr size_t OFF_WIHF = 0;                                 // 768x256 f16
static constexpr size_t OFF_WHHF = OFF_WIHF + 768UL*256*2;
static constexpr size_t OFF_WIHB = OFF_WHHF + 768UL*256*2;
static constexpr size_t OFF_WHHB = OFF_WIHB + 768UL*256*2;
static constexpr size_t OFF_WIHD = OFF_WHHB + 768UL*256*2;            // 1536x768 f16
static constexpr size_t OFF_WHHD = OFF_WIHD + 1536UL*768*2;           // 1536x512 f16
static constexpr size_t OFF_FCW  = OFF_WHHD + 1536UL*512*2;           // 32000x512 f16
static constexpr size_t OFF_XENC = OFF_FCW  + 32000UL*512*2;          // 2048x256 f16
static constexpr size_t OFF_XDEC = OFF_XENC + 2048UL*256*2;           // 1984x256 f16
static constexpr size_t OFF_GIF  = OFF_XDEC + 1984UL*256*2;           // 2048x768 f32
static constexpr size_t OFF_GIB  = OFF_GIF  + 2048UL*768*4;
static constexpr size_t OFF_GITOK= OFF_GIB  + 2048UL*768*4;           // 1984x1536 f32
static constexpr size_t OFF_GICTX= OFF_GITOK+ 1984UL*1536*4;          // 64x1536 f32
static constexpr size_t OFF_CTX32= OFF_GICTX+ 64UL*1536*4;            // 64x512 f32
static constexpr size_t OFF_CTX16= OFF_CTX32+ 64UL*512*4;             // 64x512 f16
static constexpr size_t OFF_HPP  = OFF_CTX16+ 64UL*512*2;             // 2dir x 2buf x 64x256 f16
static constexpr size_t OFF_HALL = OFF_HPP  + 2UL*2*64*256*2;         // 2048x512 f16 (rows>=1984 unused)
static constexpr size_t OFF_BAR  = OFF_HALL + 2048UL*512*2;           // 8 ints

__device__ __forceinline__ float sigmoidf_(float x) {
  return __builtin_amdgcn_rcpf(1.f + __expf(-x));
}
__device__ __forceinline__ float tanhf_(float x) {
  float xc = fminf(fmaxf(x, -10.f), 10.f);
  float e = __expf(2.f * xc);
  return (e - 1.f) * __builtin_amdgcn_rcpf(e + 1.f);
}

// Agent-scope grid barrier. Relaxed spin (atomic loads bypass stale L2 via sc1),
// single acquire fence on exit.
__device__ __forceinline__ void gbar(int* cnt, int* gen, int nwg) {
  __syncthreads();
  if (threadIdx.x == 0) {
    int g = __hip_atomic_load(gen, __ATOMIC_RELAXED, __HIP_MEMORY_SCOPE_AGENT);
    __threadfence();  // release: publish this WG's h writes (L2 writeback)
    int a = __hip_atomic_fetch_add(cnt, 1, __ATOMIC_ACQ_REL, __HIP_MEMORY_SCOPE_AGENT);
    if (a == nwg - 1) {
      __hip_atomic_store(cnt, 0, __ATOMIC_RELAXED, __HIP_MEMORY_SCOPE_AGENT);
      __hip_atomic_store(gen, g + 1, __ATOMIC_RELEASE, __HIP_MEMORY_SCOPE_AGENT);
    } else {
      while (__hip_atomic_load(gen, __ATOMIC_RELAXED, __HIP_MEMORY_SCOPE_AGENT) == g) {
        __builtin_amdgcn_s_sleep(2);
      }
    }
    __threadfence();  // acquire: invalidate stale L1/L2 before reading remote h
  }
  __syncthreads();
}

// ---------------- K1: fp32 -> fp16 weight conversion ----------------
__global__ void k_convert(const float* __restrict__ wihf, const float* __restrict__ whhf,
                          const float* __restrict__ wihb, const float* __restrict__ whhb,
                          const float* __restrict__ wihd, const float* __restrict__ whhd,
                          const float* __restrict__ fcw,
                          f16* dWihf, f16* dWhhf, f16* dWihb, f16* dWhhb,
                          f16* dWihd, f16* dWhhd, f16* dFcw) {
  const long stride = (long)gridDim.x * blockDim.x;
  for (long i = (long)blockIdx.x * blockDim.x + threadIdx.x; i < 4784128L; i += stride) {
    const float* s; f16* d; long j = i;
    if (j < 49152L)        { s = wihf; d = dWihf; }
    else if (j < 98304L)   { s = whhf; d = dWhhf; j -= 49152L; }
    else if (j < 147456L)  { s = wihb; d = dWihb; j -= 98304L; }
    else if (j < 196608L)  { s = whhb; d = dWhhb; j -= 147456L; }
    else if (j < 491520L)  { s = wihd; d = dWihd; j -= 196608L; }
    else if (j < 688128L)  { s = whhd; d = dWhhd; j -= 491520L; }
    else                   { s = fcw;  d = dFcw;  j -= 688128L; }
    float4 v = ((const float4*)s)[j];
    f16x4 o; o.x = (f16)v.x; o.y = (f16)v.y; o.z = (f16)v.z; o.w = (f16)v.w;
    ((f16x4*)d)[j] = o;
  }
}

// ---------------- K2: embedding gather + zero out[:,0,:] + barrier init ----------------
__global__ void k_gather(const int* __restrict__ srct, const int* __restrict__ trgt,
                         const float* __restrict__ embe, const float* __restrict__ embd,
                         f16* __restrict__ Xenc, f16* __restrict__ Xdec,
                         float* __restrict__ out, int* __restrict__ bar) {
  long tid = (long)blockIdx.x * blockDim.x + threadIdx.x;
  long stride = (long)gridDim.x * blockDim.x;
  if (tid < 8) bar[tid] = 0;
  for (long i = tid; i < 4032L * 64; i += stride) {
    int row = (int)(i >> 6), j4 = (int)(i & 63);
    const float* e; f16* d; int tok;
    if (row < 2048) {
      int s = row >> 6, b = row & 63;
      tok = srct[b * 32 + s]; e = embe; d = Xenc + (long)row * 256;
    } else {
      int rd = row - 2048; int t = rd >> 6, b = rd & 63;
      tok = trgt[b * 32 + t]; e = embd; d = Xdec + (long)rd * 256;
    }
    float4 v = ((const float4*)(e + (long)tok * 256))[j4];
    f16x4 o; o.x = (f16)v.x; o.y = (f16)v.y; o.z = (f16)v.z; o.w = (f16)v.w;
    ((f16x4*)d)[j4] = o;
  }
  for (long i = tid; i < 64L * 8000; i += stride) {
    long b = i / 8000, j = i % 8000;
    float4 z = make_float4(0.f, 0.f, 0.f, 0.f);
    ((float4*)(out + b * 1024000L))[j] = z;
  }
}

// ---------------- K3: generic small GEMM  C[M,N] = A[M,K]f16 @ B[N,K]f16^T (+bias) ----------------
__global__ __launch_bounds__(256) void k_gemm(const f16* __restrict__ A, int lda,
                                              const f16* __restrict__ B, int ldb,
                                              const float* __restrict__ bias,
                                              float* __restrict__ C, int ldc, int Ksteps) {
  int m0 = blockIdx.x * 64, n0 = blockIdx.y * 64;
  int lane = threadIdx.x & 63, w = threadIdx.x >> 6;
  int ar = m0 + w * 16 + (lane & 15);
  int koff = (lane >> 4) * 8;
  f32x4 acc[4] = {};
  for (int ks = 0; ks < Ksteps; ks++) {
    f16x8 a = *(const f16x8*)(A + (size_t)ar * lda + ks * 32 + koff);
#pragma unroll
    for (int ni = 0; ni < 4; ni++) {
      const f16* bp = B + (size_t)(n0 + ni * 16 + (lane & 15)) * ldb + ks * 32 + koff;
      f16x8 b = *(const f16x8*)bp;
      acc[ni] = __builtin_amdgcn_mfma_f32_16x16x32_f16(a, b, acc[ni], 0, 0, 0);
    }
  }
  int dm = m0 + w * 16 + ((lane >> 4) << 2);
  int dn0 = n0 + (lane & 15);
#pragma unroll
  for (int ni = 0; ni < 4; ni++) {
    int n = dn0 + ni * 16;
    float bv = bias ? bias[n] : 0.f;
#pragma unroll
    for (int r = 0; r < 4; r++) C[(size_t)(dm + r) * ldc + n] = acc[ni][r] + bv;
  }
}

// ---------------- K4: encoder bidir GRU recurrence (persistent, 16 WGs) ----------------
// Wave layout: dir = wg>>3, mb = (wg>>2)&1, cg = wg&3; wave (mh,ch).
// W_hh slice register-resident: wr[3][2][8] f16x8 = 192 VGPRs/thread.
__global__ __launch_bounds__(256, 1) void k_enc(
    const float* __restrict__ giF, const float* __restrict__ giB,
    const f16* __restrict__ WhhF, const f16* __restrict__ WhhB,
    const float* __restrict__ bhhF, const float* __restrict__ bhhB,
    f16* __restrict__ hpp, float* __restrict__ ctx32, f16* __restrict__ ctx16,
    int* __restrict__ bar) {
  int w = blockIdx.x;
  int dir = w >> 3, mb = (w >> 2) & 1, cg = w & 3;
  int tid = threadIdx.x, lane = tid & 63, wv = tid >> 6;
  int mh = wv >> 1, ch = wv & 1;
  const float* gi = dir ? giB : giF;
  const f16* Whh = dir ? WhhB : WhhF;
  const float* bhh = dir ? bhhB : bhhF;
  f16* hb = hpp + (size_t)dir * (2 * 64 * 256);
  { // zero ping-pong buffer 0 of this dir
    int idx0 = ((w & 7) * 256 + tid) * 8;
    f16x8 z = {};
    *(f16x8*)(hb + idx0) = z;
  }
  int colb = cg * 64 + ch * 32 + (lane & 15);
  int rowA = mb * 32 + mh * 16 + (lane & 15);
  int rowD = mb * 32 + mh * 16 + ((lane >> 4) << 2);
  int koff = (lane >> 4) * 8;

  // hoist step-invariant weights into registers
  f16x8 wr[3][2][8];
#pragma unroll
  for (int q = 0; q < 3; q++)
#pragma unroll
    for (int i = 0; i < 2; i++)
#pragma unroll
      for (int ks = 0; ks < 8; ks++)
        wr[q][i][ks] = *(const f16x8*)(Whh + (size_t)(q * 256 + colb + i * 16) * 256 + ks * 32 + koff);

  float bh[3][2];
#pragma unroll
  for (int q = 0; q < 3; q++)
#pragma unroll
    for (int i = 0; i < 2; i++) bh[q][i] = bhh[q * 256 + colb + i * 16];

  float ho[2][4] = {};
  // preload gi for step 0
  float gcur[3][2][4];
  {
    int s0 = dir ? 31 : 0;
    const float* g0 = gi + (size_t)s0 * (64 * 768);
#pragma unroll
    for (int q = 0; q < 3; q++)
#pragma unroll
      for (int i = 0; i < 2; i++)
#pragma unroll
        for (int r = 0; r < 4; r++)
          gcur[q][i][r] = g0[(size_t)(rowD + r) * 768 + q * 256 + colb + i * 16];
  }

  gbar(bar + 0, bar + 1, 16);
  for (int s = 0; s < 32; s++) {
    const f16* hr = hb + (s & 1) * (64 * 256);
    f16* hw = hb + ((s + 1) & 1) * (64 * 256);
    // a fragments
    f16x8 af[8];
#pragma unroll
    for (int ks = 0; ks < 8; ks++)
      af[ks] = *(const f16x8*)(hr + rowA * 256 + ks * 32 + koff);
    f32x4 acc[3][2] = {};
#pragma unroll
    for (int ks = 0; ks < 8; ks++) {
#pragma unroll
      for (int q = 0; q < 3; q++)
#pragma unroll
        for (int i = 0; i < 2; i++)
          acc[q][i] = __builtin_amdgcn_mfma_f32_16x16x32_f16(af[ks], wr[q][i][ks], acc[q][i], 0, 0, 0);
    }
    // prefetch next step's gi while MFMA results land
    float gn[3][2][4];
    {
      int sn = (s + 1 < 32) ? s + 1 : 31;
      int sgin = dir ? (31 - sn) : sn;
      const float* gs = gi + (size_t)sgin * (64 * 768);
#pragma unroll
      for (int q = 0; q < 3; q++)
#pragma unroll
        for (int i = 0; i < 2; i++)
#pragma unroll
          for (int r = 0; r < 4; r++)
            gn[q][i][r] = gs[(size_t)(rowD + r) * 768 + q * 256 + colb + i * 16];
    }
#pragma unroll
    for (int i = 0; i < 2; i++) {
      int col = colb + i * 16;
#pragma unroll
      for (int r = 0; r < 4; r++) {
        int m = rowD + r;
        float rg = sigmoidf_(gcur[0][i][r] + acc[0][i][r] + bh[0][i]);
        float zg = sigmoidf_(gcur[1][i][r] + acc[1][i][r] + bh[1][i]);
        float ng = tanhf_(gcur[2][i][r] + rg * (acc[2][i][r] + bh[2][i]));
        float h = (1.f - zg) * ng + zg * ho[i][r];
        ho[i][r] = h;
        hw[m * 256 + col] = (f16)h;
      }
    }
#pragma unroll
    for (int q = 0; q < 3; q++)
#pragma unroll
      for (int i = 0; i < 2; i++)
#pragma unroll
        for (int r = 0; r < 4; r++) gcur[q][i][r] = gn[q][i][r];
    gbar(bar + 0, bar + 1, 16);
  }
#pragma unroll
  for (int i = 0; i < 2; i++) {
#pragma unroll
    for (int r = 0; r < 4; r++) {
      int m = rowD + r, c = dir * 256 + colb + i * 16;
      ctx32[m * 512 + c] = ho[i][r];
      ctx16[m * 512 + c] = (f16)ho[i][r];
    }
  }
}

// ---------------- K6: decoder GRU recurrence (persistent, 32 WGs / 128 waves) ----------------
// Wave W = blockIdx*4+wv: rg = W>>5 (4 row-groups x16), cg = W&31 (32 col-groups x16).
// W_hh slice register-resident: wr[3][16] f16x8 = 192 VGPRs/thread.
__global__ __launch_bounds__(256, 1) void k_dec(
    const float* __restrict__ giTok, const float* __restrict__ giCtx,
    const f16* __restrict__ Whh, const float* __restrict__ bhh,
    const float* __restrict__ ctx32, const f16* __restrict__ ctx16,
    f16* __restrict__ Hall, int* __restrict__ bar) {
  int tid = threadIdx.x, lane = tid & 63, wv = tid >> 6;
  int W = blockIdx.x * 4 + wv;
  int rg = W >> 5, cg = W & 31;
  int colb = cg * 16 + (lane & 15);
  int rowA = rg * 16 + (lane & 15);
  int rowD = rg * 16 + ((lane >> 4) << 2);
  int koff = (lane >> 4) * 8;

  // hoist step-invariant weights
  f16x8 wr[3][16];
#pragma unroll
  for (int q = 0; q < 3; q++)
#pragma unroll
    for (int ks = 0; ks < 16; ks++)
      wr[q][ks] = *(const f16x8*)(Whh + (size_t)(q * 512 + colb) * 512 + ks * 32 + koff);

  float bh[3], gc[3][4], ho[4];
#pragma unroll
  for (int q = 0; q < 3; q++) {
    bh[q] = bhh[q * 512 + colb];
#pragma unroll
    for (int r = 0; r < 4; r++)
      gc[q][r] = giCtx[(size_t)(rowD + r) * 1536 + q * 512 + colb];
  }
#pragma unroll
  for (int r = 0; r < 4; r++) ho[r] = ctx32[(rowD + r) * 512 + colb];

  // preload token-gi for t=0
  float gcur[3][4];
#pragma unroll
  for (int q = 0; q < 3; q++)
#pragma unroll
    for (int r = 0; r < 4; r++)
      gcur[q][r] = giTok[(size_t)(rowD + r) * 1536 + q * 512 + colb];

  for (int t = 0; t < 31; t++) {
    const f16* hr = t ? (Hall + (size_t)(t - 1) * (64 * 512)) : ctx16;
    f16* hw = Hall + (size_t)t * (64 * 512);
    f16x8 af[16];
#pragma unroll
    for (int ks = 0; ks < 16; ks++)
      af[ks] = *(const f16x8*)(hr + rowA * 512 + ks * 32 + koff);
    f32x4 acc[3] = {};
#pragma unroll
    for (int ks = 0; ks < 16; ks++) {
#pragma unroll
      for (int q = 0; q < 3; q++)
        acc[q] = __builtin_amdgcn_mfma_f32_16x16x32_f16(af[ks], wr[q][ks], acc[q], 0, 0, 0);
    }
    // prefetch next token-gi
    float gn[3][4];
    {
      int tn = (t + 1 < 31) ? t + 1 : 30;
      const float* gs = giTok + (size_t)tn * (64 * 1536);
#pragma unroll
      for (int q = 0; q < 3; q++)
#pragma unroll
        for (int r = 0; r < 4; r++)
          gn[q][r] = gs[(size_t)(rowD + r) * 1536 + q * 512 + colb];
    }
#pragma unroll
    for (int r = 0; r < 4; r++) {
      int m = rowD + r;
      float rg_ = sigmoidf_(gcur[0][r] + gc[0][r] + acc[0][r] + bh[0]);
      float zg = sigmoidf_(gcur[1][r] + gc[1][r] + acc[1][r] + bh[1]);
      float ng = tanhf_(gcur[2][r] + gc[2][r] + rg_ * (acc[2][r] + bh[2]));
      float h = (1.f - zg) * ng + zg * ho[r];
      ho[r] = h;
      hw[m * 512 + colb] = (f16)h;
    }
#pragma unroll
    for (int q = 0; q < 3; q++)
#pragma unroll
      for (int r = 0; r < 4; r++) gcur[q][r] = gn[q][r];
    gbar(bar + 2, bar + 3, 32);
  }
}

// ---------------- K7: FC GEMM  out[b, t+1, :] = Hall[t*64+b, :] @ fcW^T + fcb ----------------
__global__ __launch_bounds__(256, 2) void k_fc(const f16* __restrict__ Hall, const f16* __restrict__ Wfc,
                                               const float* __restrict__ fcb, float* __restrict__ out) {
  __shared__ f16 As[128 * 64];
  __shared__ f16 Bs[128 * 64];
  int bid = blockIdx.x;
  int by = bid / 250, bx = bid % 250;
  int m0 = by * 128, n0 = bx * 128;
  int tid = threadIdx.x, lane = tid & 63, wv = tid >> 6;
  int wm = wv >> 1, wn = wv & 1;
  f32x4 acc[4][4] = {};
  for (int kk = 0; kk < 8; kk++) {
    f16x8 ra[4], rb[4];
#pragma unroll
    for (int c = 0; c < 4; c++) {
      int seg = c * 256 + tid;
      int row = seg >> 3, ko = (seg & 7) * 8;
      ra[c] = *(const f16x8*)(Hall + (size_t)(m0 + row) * 512 + kk * 64 + ko);
      rb[c] = *(const f16x8*)(Wfc + (size_t)(n0 + row) * 512 + kk * 64 + ko);
    }
    __syncthreads();
#pragma unroll
    for (int c = 0; c < 4; c++) {
      int seg = c * 256 + tid;
      *(f16x8*)&As[seg * 8] = ra[c];
      *(f16x8*)&Bs[seg * 8] = rb[c];
    }
    __syncthreads();
#pragma unroll
    for (int ks = 0; ks < 2; ks++) {
      f16x8 af[4], bf[4];
#pragma unroll
      for (int mi = 0; mi < 4; mi++)
        af[mi] = *(const f16x8*)&As[(wm * 64 + mi * 16 + (lane & 15)) * 64 + ks * 32 + (lane >> 4) * 8];
#pragma unroll
      for (int ni = 0; ni < 4; ni++)
        bf[ni] = *(const f16x8*)&Bs[(wn * 64 + ni * 16 + (lane & 15)) * 64 + ks * 32 + (lane >> 4) * 8];
#pragma unroll
      for (int mi = 0; mi < 4; mi++) {
#pragma unroll
        for (int ni = 0; ni < 4; ni++)
          acc[mi][ni] = __builtin_amdgcn_mfma_f32_16x16x32_f16(af[mi], bf[ni], acc[mi][ni], 0, 0, 0);
      }
    }
  }
  int dn0 = n0 + wn * 64 + (lane & 15);
  float bv[4];
#pragma unroll
  for (int ni = 0; ni < 4; ni++) bv[ni] = fcb[dn0 + ni * 16];
#pragma unroll
  for (int mi = 0; mi < 4; mi++) {
    int mbase = m0 + wm * 64 + mi * 16 + ((lane >> 4) << 2);
#pragma unroll
    for (int r = 0; r < 4; r++) {
      int m = mbase + r;
      if (m < 1984) {
        int t = m >> 6, b = m & 63;
        float* orow = out + (size_t)b * 1024000 + (size_t)(t + 1) * 32000;
#pragma unroll
        for (int ni = 0; ni < 4; ni++) orow[dn0 + ni * 16] = acc[mi][ni][r] + bv[ni];
      }
    }
  }
}

extern "C" void kernel_launch(void* const* d_in, const int* in_sizes, int n_in,
                              void* d_out, int out_size, void* d_ws, size_t ws_size,
                              hipStream_t stream) {
  const int*   srct = (const int*)d_in[0];
  const int*   trgt = (const int*)d_in[1];
  const float* embe = (const float*)d_in[2];
  const float* wihf = (const float*)d_in[3];
  const float* whhf = (const float*)d_in[4];
  const float* bihf = (const float*)d_in[5];
  const float* bhhf = (const float*)d_in[6];
  const float* wihb = (const float*)d_in[7];
  const float* whhb = (const float*)d_in[8];
  const float* bihb = (const float*)d_in[9];
  const float* bhhb = (const float*)d_in[10];
  const float* embd = (const float*)d_in[11];
  const float* wihd = (const float*)d_in[12];
  const float* whhd = (const float*)d_in[13];
  const float* bihd = (const float*)d_in[14];
  const float* bhhd = (const float*)d_in[15];
  const float* fcw  = (const float*)d_in[16];
  const float* fcb  = (const float*)d_in[17];
  float* out = (float*)d_out;
  char* ws = (char*)d_ws;

  f16* W_ihf = (f16*)(ws + OFF_WIHF);
  f16* W_hhf = (f16*)(ws + OFF_WHHF);
  f16* W_ihb = (f16*)(ws + OFF_WIHB);
  f16* W_hhb = (f16*)(ws + OFF_WHHB);
  f16* W_ihd = (f16*)(ws + OFF_WIHD);
  f16* W_hhd = (f16*)(ws + OFF_WHHD);
  f16* Wfc   = (f16*)(ws + OFF_FCW);
  f16* Xenc  = (f16*)(ws + OFF_XENC);
  f16* Xdec  = (f16*)(ws + OFF_XDEC);
  float* giF   = (float*)(ws + OFF_GIF);
  float* giB   = (float*)(ws + OFF_GIB);
  float* giTok = (float*)(ws + OFF_GITOK);
  float* giCtx = (float*)(ws + OFF_GICTX);
  float* ctx32 = (float*)(ws + OFF_CTX32);
  f16*   ctx16 = (f16*)(ws + OFF_CTX16);
  f16*   hpp   = (f16*)(ws + OFF_HPP);
  f16*   Hall  = (f16*)(ws + OFF_HALL);
  int*   bar   = (int*)(ws + OFF_BAR);

  k_convert<<<2048, 256, 0, stream>>>(wihf, whhf, wihb, whhb, wihd, whhd, fcw,
                                      W_ihf, W_hhf, W_ihb, W_hhb, W_ihd, W_hhd, Wfc);
  k_gather<<<1024, 256, 0, stream>>>(srct, trgt, embe, embd, Xenc, Xdec, out, bar);
  k_gemm<<<dim3(32, 12), 256, 0, stream>>>(Xenc, 256, W_ihf, 256, bihf, giF, 768, 8);
  k_gemm<<<dim3(32, 12), 256, 0, stream>>>(Xenc, 256, W_ihb, 256, bihb, giB, 768, 8);
  k_gemm<<<dim3(31, 24), 256, 0, stream>>>(Xdec, 256, W_ihd, 768, nullptr, giTok, 1536, 8);
  k_enc<<<16, 256, 0, stream>>>(giF, giB, W_hhf, W_hhb, bhhf, bhhb, hpp, ctx32, ctx16, bar);
  k_gemm<<<dim3(1, 24), 256, 0, stream>>>(ctx16, 512, W_ihd + 256, 768, bihd, giCtx, 1536, 16);
  k_dec<<<32, 256, 0, stream>>>(giTok, giCtx, W_hhd, bhhd, ctx32, ctx16, Hall, bar);
  k_fc<<<4000, 256, 0, stream>>>(Hall, Wfc, fcb, out);
}